// Round 9
// baseline (527.128 us; speedup 1.0000x reference)
//
#include <hip/hip_runtime.h>
#include <hip/hip_bf16.h>

typedef unsigned short u16;
typedef __attribute__((ext_vector_type(4))) float f32x4;
typedef __attribute__((ext_vector_type(16))) float f32x16;
typedef __attribute__((ext_vector_type(8))) short bf16x8;
typedef __attribute__((ext_vector_type(4))) unsigned u32x4;

#define B_ 2
#define S_ 2048
#define HID_ 2048
#define H_ 32
#define KVH_ 4
#define D_ 128
#define M_ 4096
#define NQ_ 4096
#define NKV_ 512

typedef const __attribute__((address_space(1))) void gconst_void;
typedef __attribute__((address_space(3))) void lds_void;

static __device__ __forceinline__ void gload_lds16(const void* g, void* l) {
  __builtin_amdgcn_global_load_lds((gconst_void*)g, (lds_void*)l, 16, 0, 0);
}

#define WAITV(N) asm volatile("s_waitcnt vmcnt(" #N ")" ::: "memory")
#define WAITL0() asm volatile("s_waitcnt lgkmcnt(0)" ::: "memory")
#define SBAR() __builtin_amdgcn_s_barrier()
#define SCHED0() __builtin_amdgcn_sched_barrier(0)
#define CFENCE() asm volatile("" ::: "memory")

static __device__ __forceinline__ u16 f2b(float f) {
  union { float f; unsigned i; } x; x.f = f;
  return (u16)((x.i + 0x7fffu + ((x.i >> 16) & 1u)) >> 16);
}
static __device__ __forceinline__ float b2f(u16 u) {
  union { unsigned i; float f; } x; x.i = ((unsigned)u) << 16;
  return x.f;
}
static __device__ __forceinline__ float max3f(float a, float b, float c) {
  float d;
  asm("v_max3_f32 %0, %1, %2, %3" : "=v"(d) : "v"(a), "v"(b), "v"(c));
  return d;
}

// ---------------- fused prep: fp32->bf16 cvt + 4 weight transposes ----------------
static __device__ __forceinline__ void tr_tile(const float* __restrict__ W,
    u16* __restrict__ Wt, int K, int N, int n0, int k0, u16 (*t)[72]) {
  int tid = threadIdx.x;
  int r = tid >> 4;
  int c4 = (tid & 15) * 4;
#pragma unroll
  for (int i = 0; i < 4; i++) {
    int k = r + i * 16;
    float4 v = *reinterpret_cast<const float4*>(W + (size_t)(k0 + k) * N + n0 + c4);
    t[k][c4 + 0] = f2b(v.x); t[k][c4 + 1] = f2b(v.y);
    t[k][c4 + 2] = f2b(v.z); t[k][c4 + 3] = f2b(v.w);
  }
  __syncthreads();
#pragma unroll
  for (int i = 0; i < 4; i++) {
    int n = r + i * 16;
    ushort4 o;
    o.x = t[c4 + 0][n]; o.y = t[c4 + 1][n]; o.z = t[c4 + 2][n]; o.w = t[c4 + 3][n];
    *reinterpret_cast<ushort4*>(Wt + (size_t)(n0 + n) * K + k0 + c4) = o;
  }
}

__global__ __launch_bounds__(256) void k_prep(const float* __restrict__ hidden, u16* __restrict__ hb,
    const float* __restrict__ qw, u16* __restrict__ qwt,
    const float* __restrict__ kw, u16* __restrict__ kwt,
    const float* __restrict__ vw, u16* __restrict__ vwt,
    const float* __restrict__ ow, u16* __restrict__ owt) {
  __shared__ u16 t[64][72];
  const int bid = blockIdx.x;
  if (bid < 2048) {
    const int n4 = M_ * HID_ / 4;
    int i = bid * 256 + threadIdx.x;
    const int stride = 2048 * 256;
    for (; i < n4; i += stride) {
      float4 v = reinterpret_cast<const float4*>(hidden)[i];
      ushort4 o;
      o.x = f2b(v.x); o.y = f2b(v.y); o.z = f2b(v.z); o.w = f2b(v.w);
      reinterpret_cast<ushort4*>(hb)[i] = o;
    }
  } else if (bid < 4096) {
    int l = bid - 2048;
    tr_tile(qw, qwt, HID_, NQ_, (l & 63) * 64, (l >> 6) * 64, t);
  } else if (bid < 4352) {
    int l = bid - 4096;
    tr_tile(kw, kwt, HID_, NKV_, (l & 7) * 64, (l >> 3) * 64, t);
  } else if (bid < 4608) {
    int l = bid - 4352;
    tr_tile(vw, vwt, HID_, NKV_, (l & 7) * 64, (l >> 3) * 64, t);
  } else {
    int l = bid - 4608;
    tr_tile(ow, owt, NQ_, HID_, (l & 31) * 64, (l >> 5) * 64, t);
  }
}

// ---- 128x128 bf16 GEMM core, counted-vmcnt dbuf pipeline (T4) ----
__device__ __forceinline__ void gemm_core(const u16* __restrict__ A, const u16* __restrict__ Bt,
                                          int K, int m0, int n0,
                                          u16* As, u16* Bs, f32x4 (&acc)[4][4]) {
  const int tid = threadIdx.x;
  const int lane = tid & 63;
  const int wid = tid >> 6;
  const int wr = wid >> 1, wc = wid & 1;
  const int lrow = lane & 15;
  const int hi = lane >> 4;
  const f32x4 zz = {0.f, 0.f, 0.f, 0.f};
#pragma unroll
  for (int i = 0; i < 4; i++)
#pragma unroll
    for (int j = 0; j < 4; j++) acc[i][j] = zz;

  const int srow = tid >> 3;
  const int sc16 = tid & 7;
  const int nk = K >> 6;
  int cur = 0;

#pragma unroll
  for (int rep = 0; rep < 4; rep++) {
    int row = rep * 32 + srow;
    int gcol = ((sc16 ^ (row & 7)) << 3);
    gload_lds16(A + (size_t)(m0 + row) * K + gcol, As + row * 64 + sc16 * 8);
    gload_lds16(Bt + (size_t)(n0 + row) * K + gcol, Bs + row * 64 + sc16 * 8);
  }

  for (int t = 0; t < nk; t++) {
    if (t + 1 < nk) {
      int nxt = cur ^ 1;
      int kb = (t + 1) << 6;
#pragma unroll
      for (int rep = 0; rep < 4; rep++) {
        int row = rep * 32 + srow;
        int gcol = kb + ((sc16 ^ (row & 7)) << 3);
        gload_lds16(A + (size_t)(m0 + row) * K + gcol, As + nxt * 8192 + row * 64 + sc16 * 8);
        gload_lds16(Bt + (size_t)(n0 + row) * K + gcol, Bs + nxt * 8192 + row * 64 + sc16 * 8);
      }
      WAITV(8);
    } else {
      WAITV(0);
    }
    SCHED0(); SBAR(); CFENCE(); SCHED0();

    const u16* Ac = As + cur * 8192;
    const u16* Bc = Bs + cur * 8192;
#pragma unroll
    for (int kc = 0; kc < 2; kc++) {
      bf16x8 af[4], bfr[4];
#pragma unroll
      for (int i = 0; i < 4; i++) {
        int row = wr * 64 + i * 16 + lrow;
        af[i] = *reinterpret_cast<const bf16x8*>(Ac + row * 64 + ((((kc << 2) + hi) ^ (row & 7)) << 3));
      }
#pragma unroll
      for (int j = 0; j < 4; j++) {
        int row = wc * 64 + j * 16 + lrow;
        bfr[j] = *reinterpret_cast<const bf16x8*>(Bc + row * 64 + ((((kc << 2) + hi) ^ (row & 7)) << 3));
      }
#pragma unroll
      for (int i = 0; i < 4; i++)
#pragma unroll
        for (int j = 0; j < 4; j++)
          acc[i][j] = __builtin_amdgcn_mfma_f32_16x16x32_bf16(af[i], bfr[j], acc[i][j], 0, 0, 0);
    }
    SBAR(); SCHED0();
    cur ^= 1;
  }
}

// ---------------- Q projection: 256x256 4-phase template, counted vmcnt ----------------
__global__ __launch_bounds__(512, 2) void k_gemm_q8(const u16* __restrict__ A,
    const u16* __restrict__ Bt, u16* __restrict__ qb) {
  __shared__ u16 Ash[2][2][128 * 64];
  __shared__ u16 Bsh[2][2][128 * 64];
  const int bid = blockIdx.x;
  const int wg = (bid & 7) * 32 + (bid >> 3);
  const int mt = wg & 15, nt = wg >> 4;
  const int m0 = mt * 256, n0 = nt * 256;
  const int K = HID_, nk = K >> 6;
  const int tid = threadIdx.x, lane = tid & 63;
  const int wv = tid >> 6, wr = wv >> 2, wc = wv & 3;
  const int lrow = lane & 15, hi4 = lane >> 4;

  const int s0r = tid >> 3, sc = tid & 7;
  const int s1r = (tid + 512) >> 3;

  auto stgA = [&](int h, int t, int d) {
    gload_lds16(A + (size_t)(m0 + h * 128 + s0r) * K + t * 64 + ((sc ^ (s0r & 7)) << 3),
                &Ash[d][h][s0r * 64 + sc * 8]);
    gload_lds16(A + (size_t)(m0 + h * 128 + s1r) * K + t * 64 + ((sc ^ (s1r & 7)) << 3),
                &Ash[d][h][s1r * 64 + sc * 8]);
  };
  auto stgB = [&](int h, int t, int d) {
    gload_lds16(Bt + (size_t)(n0 + h * 128 + s0r) * K + t * 64 + ((sc ^ (s0r & 7)) << 3),
                &Bsh[d][h][s0r * 64 + sc * 8]);
    gload_lds16(Bt + (size_t)(n0 + h * 128 + s1r) * K + t * 64 + ((sc ^ (s1r & 7)) << 3),
                &Bsh[d][h][s1r * 64 + sc * 8]);
  };

  f32x4 acc[8][4];
  const f32x4 zz = {0.f, 0.f, 0.f, 0.f};
#pragma unroll
  for (int f = 0; f < 8; f++)
#pragma unroll
    for (int j = 0; j < 4; j++) acc[f][j] = zz;

  bf16x8 af0[4][2], af1[4][2], bfr[2][2];

  auto lda = [&](bf16x8 (&dst)[4][2], int mh, int d) {
#pragma unroll
    for (int fi = 0; fi < 4; fi++) {
      int row = fi * 32 + wr * 16 + lrow;
#pragma unroll
      for (int kk = 0; kk < 2; kk++)
        dst[fi][kk] = *reinterpret_cast<const bf16x8*>(
            &Ash[d][mh][row * 64 + ((((kk << 2) + hi4) ^ (row & 7)) << 3)]);
    }
  };
  auto ldb = [&](int nh, int d) {
#pragma unroll
    for (int ji = 0; ji < 2; ji++) {
      int row = ji * 64 + wc * 16 + lrow;
#pragma unroll
      for (int kk = 0; kk < 2; kk++)
        bfr[ji][kk] = *reinterpret_cast<const bf16x8*>(
            &Bsh[d][nh][row * 64 + ((((kk << 2) + hi4) ^ (row & 7)) << 3)]);
    }
  };
  auto mq = [&](bf16x8 (&afh)[4][2], int mh, int nh) {
    __builtin_amdgcn_s_setprio(1);
#pragma unroll
    for (int kk = 0; kk < 2; kk++)
#pragma unroll
      for (int fi = 0; fi < 4; fi++)
#pragma unroll
        for (int ji = 0; ji < 2; ji++)
          acc[mh * 4 + fi][nh * 2 + ji] = __builtin_amdgcn_mfma_f32_16x16x32_bf16(
              afh[fi][kk], bfr[ji][kk], acc[mh * 4 + fi][nh * 2 + ji], 0, 0, 0);
    __builtin_amdgcn_s_setprio(0);
  };

  stgA(0, 0, 0); stgA(1, 0, 0); stgB(0, 0, 0); stgB(1, 0, 0);
  WAITV(2); SCHED0();
  SBAR(); SCHED0();

  for (int t = 0; t < nk; t++) {
    const int d = t & 1, nd = d ^ 1;
    const bool pre = (t + 1 < nk);
    lda(af0, 0, d); ldb(0, d);
    if (pre) stgA(0, t + 1, nd);
    SCHED0(); SBAR();
    WAITL0(); SCHED0();
    mq(af0, 0, 0);
    SBAR(); SCHED0();
    lda(af1, 1, d);
    if (pre) stgA(1, t + 1, nd);
    WAITV(4); SCHED0(); SBAR();
    WAITL0(); SCHED0();
    mq(af1, 1, 0);
    SBAR(); SCHED0();
    ldb(1, d);
    if (pre) stgB(0, t + 1, nd);
    SCHED0(); SBAR();
    WAITL0(); SCHED0();
    mq(af1, 1, 1);
    SBAR(); SCHED0();
    if (pre) stgB(1, t + 1, nd);
    WAITV(2); SCHED0(); SBAR();
    mq(af0, 0, 1);
    SBAR(); SCHED0();
  }

  const int lr4 = hi4 * 4, lc = lane & 15;
#pragma unroll
  for (int f = 0; f < 8; f++)
#pragma unroll
    for (int j = 0; j < 4; j++)
#pragma unroll
      for (int rr = 0; rr < 4; rr++) {
        int m = m0 + f * 32 + wr * 16 + lr4 + rr;
        int ncol = n0 + j * 64 + wc * 16 + lc;
        int b = m >> 11, s = m & (S_ - 1);
        int head = ncol >> 7, dd = ncol & 127;
        qb[(((size_t)b * H_ + head) * S_ + s) * D_ + dd] = f2b(acc[f][j][rr]);
      }
}

// ---------------- K/V projections (128^2 core), grid 256 1D swizzled ----------------
__global__ __launch_bounds__(256, 2) void k_gemm_kv(const u16* __restrict__ hb,
    const u16* __restrict__ kwt, const u16* __restrict__ vwt,
    u16* __restrict__ kb, u16* __restrict__ vb) {
  __shared__ u16 As[2 * 128 * 64], Bs[2 * 128 * 64];
  const int bid = blockIdx.x;
  const int wg = (bid & 7) * 32 + (bid >> 3);
  const int mt = wg & 31, nt = wg >> 5;
  const bool isv = nt >= 4;
  const int head = isv ? nt - 4 : nt;
  const u16* Bt = isv ? vwt : kwt;
  f32x4 acc[4][4];
  gemm_core(hb, Bt, HID_, mt * 128, head * 128, As, Bs, acc);
  const int lane = threadIdx.x & 63;
  const int wid = threadIdx.x >> 6;
  const int wr = wid >> 1, wc = wid & 1;
  const int lr4 = (lane >> 4) * 4, lc = lane & 15;
#pragma unroll
  for (int i = 0; i < 4; i++)
#pragma unroll
    for (int j = 0; j < 4; j++)
#pragma unroll
      for (int r = 0; r < 4; r++) {
        int m = mt * 128 + wr * 64 + i * 16 + lr4 + r;
        int d = wc * 64 + j * 16 + lc;
        int b = m >> 11, s = m & (S_ - 1);
        u16 val = f2b(acc[i][j][r]);
        if (isv) vb[(((size_t)b * KVH_ + head) * D_ + d) * S_ + s] = val;  // transposed
        else     kb[(((size_t)b * KVH_ + head) * S_ + s) * D_ + d] = val;
      }
}

// ---------------- O projection (128^2 core), grid 512 1D swizzled ----------------
__global__ __launch_bounds__(256, 2) void k_gemm_o(const u16* __restrict__ ab,
    const u16* __restrict__ owt, float* __restrict__ out) {
  __shared__ u16 As[2 * 128 * 64], Bs[2 * 128 * 64];
  const int bid = blockIdx.x;
  const int wg = (bid & 7) * 64 + (bid >> 3);
  const int mt = wg & 31, nt = wg >> 5;
  f32x4 acc[4][4];
  gemm_core(ab, owt, NQ_, mt * 128, nt * 128, As, Bs, acc);
  const int lane = threadIdx.x & 63;
  const int wid = threadIdx.x >> 6;
  const int wr = wid >> 1, wc = wid & 1;
  const int lr4 = (lane >> 4) * 4, lc = lane & 15;
#pragma unroll
  for (int i = 0; i < 4; i++)
#pragma unroll
    for (int j = 0; j < 4; j++)
#pragma unroll
      for (int r = 0; r < 4; r++) {
        int m = mt * 128 + wr * 64 + i * 16 + lr4 + r;
        int n = nt * 128 + wc * 64 + j * 16 + lc;
        out[(size_t)m * HID_ + n] = acc[i][j][r];
      }
}

// ---------------- RMSNorm + RoPE; Q additionally pre-scaled by scale*log2e ----------------
__global__ __launch_bounds__(256) void k_norm_rope(u16* __restrict__ qb, u16* __restrict__ kb,
    const float* __restrict__ cosp, const float* __restrict__ sinp,
    const float* __restrict__ qnw, const float* __restrict__ knw) {
  int row = blockIdx.x * 4 + (threadIdx.x >> 6);
  int lane = threadIdx.x & 63;
  const int QROWS = B_ * H_ * S_;
  u16* ptr; const float* nw; int b, s; float os;
  if (row < QROWS) {
    ptr = qb + (size_t)row * D_; nw = qnw;
    s = row & (S_ - 1); b = row / (H_ * S_);
    os = 0.08838834764831845f * 1.44269504088896340f;
  } else {
    int r2 = row - QROWS;
    ptr = kb + (size_t)r2 * D_; nw = knw;
    s = r2 & (S_ - 1); b = r2 / (KVH_ * S_);
    os = 1.0f;
  }
  int d = lane * 2;
  float x0 = b2f(ptr[d]), x1 = b2f(ptr[d + 1]);
  float ss = x0 * x0 + x1 * x1;
#pragma unroll
  for (int m = 1; m < 64; m <<= 1) ss += __shfl_xor(ss, m);
  float inv = rsqrtf(ss * (1.0f / 128.0f) + 1e-6f) * os;
  x0 = x0 * inv * nw[d]; x1 = x1 * inv * nw[d + 1];
  float p0 = __shfl_xor(x0, 32), p1 = __shfl_xor(x1, 32);
  float r0 = (lane < 32) ? -p0 : p0;
  float r1 = (lane < 32) ? -p1 : p1;
  const float* cp = cosp + ((size_t)b * S_ + s) * D_;
  const float* sp = sinp + ((size_t)b * S_ + s) * D_;
  ptr[d]     = f2b(x0 * cp[d]     + r0 * sp[d]);
  ptr[d + 1] = f2b(x1 * cp[d + 1] + r1 * sp[d + 1]);
}

// ------ causal GQA flash attention: 16 warps, paired q-tiles CONCURRENT (kv-split) ------
// grid 256, 1024 thr. Group A (warps 0-7): heavy tile qh=7-qx, kv [0,18).
// Group B (warps 8-15): heavy tile kv [18,Nh), then light tile ql=qx kv [0,Nl).
// (Nh-18)+Nl = 18 for all qx -> both groups run exactly 18 barrier-locked iters.
// Heavy-tile partials merged via LSE: B dumps (O bf16-packed, m, l) to scratch at
// its switch iter; A merges in epilogue. B writes light tile directly.
__global__ __launch_bounds__(1024, 1) void k_attn(const u16* __restrict__ q,
    const u16* __restrict__ k, const u16* __restrict__ vt, u16* __restrict__ out,
    u16* __restrict__ scrO, float* __restrict__ scrML) {
  __shared__ u16 Kb[2 * 2 * 64 * 128];   // [group][dbuf][64x128]
  __shared__ u16 Vb[2 * 2 * 128 * 64];   // [group][dbuf][128x64]
  const int bid = blockIdx.x;
  const int wgid = (bid & 7) * 32 + (bid >> 3);
  const int qx = wgid & 3, bh = wgid >> 2;
  const int b = bh >> 5, h = bh & 31;
  const int kvh = h >> 3;
  const int tid = threadIdx.x;
  const int g = tid >> 9;              // 0 = A, 1 = B
  const int gtid = tid & 511;
  const int lane = tid & 63, w = gtid >> 6;
  const int lq = lane & 31, hi = lane >> 5;
  const u16* qp  = q  + ((size_t)(b * H_ + h) * S_) * D_;
  const u16* kp  = k  + ((size_t)(b * KVH_ + kvh) * S_) * D_;
  const u16* vtp = vt + ((size_t)(b * KVH_ + kvh) * D_) * S_;

  const int Nh = 32 - 4 * qx;
  const int sB = Nh - 18;              // B's switch iter (2..14)
  const int q0h = (7 - qx) * 256;
  const int q0l = qx * 256;

  const int rowKa = gtid >> 4;
  const int colK  = ((gtid & 15) ^ (rowKa & 15)) << 3;
  const int rowVa = gtid >> 3;
  const int colV  = ((gtid & 7) ^ (rowVa & 7)) << 3;
  u16* KG = Kb + g * 16384;
  u16* VG = Vb + g * 16384;

  auto nmap = [&](int i) { return (g == 0) ? i : ((i < sB) ? 18 + i : i - sB); };
  auto stage = [&](int n, int cu) {
    u16* kd = KG + cu * 8192 + gtid * 8;
    u16* vd = VG + cu * 8192 + gtid * 8;
    const u16* ks = kp + (size_t)(n * 64 + rowKa) * D_ + colK;
    gload_lds16(ks, kd);
    gload_lds16(ks + 32 * D_, kd + 4096);
    const u16* vs = vtp + (size_t)rowVa * S_ + n * 64 + colV;
    gload_lds16(vs, vd);
    gload_lds16(vs + (size_t)64 * S_, vd + 4096);
  };

  const f32x16 z16 = {0.f};
  int q0 = q0h;                         // both groups start on heavy tile
  bf16x8 qf[8];
#pragma unroll
  for (int ds = 0; ds < 8; ds++)
    qf[ds] = *reinterpret_cast<const bf16x8*>(qp + (size_t)(q0 + 32 * w + lq) * D_ + ds * 16 + hi * 8);

  f32x16 oacc[4];
#pragma unroll
  for (int dt = 0; dt < 4; dt++) oacc[dt] = z16;
  float mrun = -1e30f, lrun = 0.f;

  stage(nmap(0), 0);
  int cur = 0;

  for (int i = 0; i < 18; i++) {
    if (i < 17) {
      stage(nmap(i + 1), cur ^ 1);
      WAITV(4);
    } else {
      WAITV(0);
    }
    SCHED0(); SBAR(); CFENCE(); SCHED0();

    // group B: switch heavy -> light tile
    if (g == 1 && i == sB) {
      unsigned* o32 = (unsigned*)scrO + (size_t)bid * 16384;
#pragma unroll
      for (int dt = 0; dt < 4; dt++)
#pragma unroll
        for (int r = 0; r < 16; r += 2) {
          unsigned pk;
          asm("v_cvt_pk_bf16_f32 %0, %1, %2" : "=v"(pk)
              : "v"(oacc[dt][r]), "v"(oacc[dt][r + 1]));
          int rowb = 32 * w + (r & 3) + 8 * (r >> 2) + 4 * hi;
          o32[(dt * 32 + lq) * 128 + (rowb >> 1)] = pk;
        }
      if (hi == 0) {
        scrML[(size_t)bid * 512 + 32 * w + lq] = mrun;
        scrML[(size_t)bid * 512 + 256 + 32 * w + lq] = lrun;
      }
#pragma unroll
      for (int dt = 0; dt < 4; dt++) oacc[dt] = z16;
      mrun = -1e30f; lrun = 0.f;
      q0 = q0l;
#pragma unroll
      for (int ds = 0; ds < 8; ds++)
        qf[ds] = *reinterpret_cast<const bf16x8*>(
            qp + (size_t)(q0 + 32 * w + lq) * D_ + ds * 16 + hi * 8);
    }

    const int n0 = nmap(i) * 64;
    const int qg = q0 + 32 * w + lq;
    const u16* Kc = KG + cur * 8192;
    const u16* Vc = VG + cur * 8192;

    const bool skip = (n0 > q0 + 32 * w + 31);
    if (!skip) {
      const bool needmask = (n0 + 63 > q0 + 32 * w);

      f32x16 sacc[2];
      sacc[0] = z16; sacc[1] = z16;
#pragma unroll
      for (int ds = 0; ds < 8; ds++) {
        const int sl = (((ds << 1) + hi) ^ (lq & 15)) << 3;
        bf16x8 ka0 = *reinterpret_cast<const bf16x8*>(Kc + lq * 128 + sl);
        bf16x8 ka1 = *reinterpret_cast<const bf16x8*>(Kc + (lq + 32) * 128 + sl);
        __builtin_amdgcn_s_setprio(1);
        sacc[0] = __builtin_amdgcn_mfma_f32_32x32x16_bf16(ka0, qf[ds], sacc[0], 0, 0, 0);
        sacc[1] = __builtin_amdgcn_mfma_f32_32x32x16_bf16(ka1, qf[ds], sacc[1], 0, 0, 0);
        __builtin_amdgcn_s_setprio(0);
      }

      if (needmask) {
#pragma unroll
        for (int t = 0; t < 2; t++)
#pragma unroll
          for (int r = 0; r < 16; r++) {
            int kvg = n0 + 32 * t + (r & 3) + 8 * (r >> 2) + 4 * hi;
            if (kvg > qg) sacc[t][r] = -1e30f;
          }
      }
      float tm = fmaxf(sacc[0][0], sacc[0][1]);
#pragma unroll
      for (int i2 = 1; i2 < 16; i2++) {
        const int e0 = 2 * i2, e1 = 2 * i2 + 1;
        tm = max3f(tm, sacc[e0 >> 4][e0 & 15], sacc[e1 >> 4][e1 & 15]);
      }
      tm = fmaxf(tm, __shfl_xor(tm, 32));
      if (__any(tm > mrun + 8.f)) {   // defer-max (T13), log2 units
        float mn = fmaxf(mrun, tm);
        float al = exp2f(mrun - mn);
        mrun = mn;
        lrun *= al;
#pragma unroll
        for (int r = 0; r < 16; r++) {
          float ar = __shfl(al, (r & 3) + 8 * (r >> 2) + 4 * hi);
#pragma unroll
          for (int dt = 0; dt < 4; dt++) oacc[dt][r] *= ar;
        }
      }
      float rs = 0.f;
#pragma unroll
      for (int t = 0; t < 2; t++)
#pragma unroll
        for (int r = 0; r < 16; r++) {
          float pv = exp2f(sacc[t][r] - mrun);
          sacc[t][r] = pv;
          rs += pv;
        }
      rs += __shfl_xor(rs, 32);
      lrun += rs;

      u32x4 pa[4];
#pragma unroll
      for (int t = 0; t < 2; t++)
#pragma unroll
        for (int ksl = 0; ksl < 2; ksl++) {
          unsigned wa, wb, wc2, wd;
          asm("v_cvt_pk_bf16_f32 %0, %1, %2" : "=v"(wa)
              : "v"(sacc[t][8 * ksl + 0]), "v"(sacc[t][8 * ksl + 1]));
          asm("v_cvt_pk_bf16_f32 %0, %1, %2" : "=v"(wb)
              : "v"(sacc[t][8 * ksl + 2]), "v"(sacc[t][8 * ksl + 3]));
          asm("v_cvt_pk_bf16_f32 %0, %1, %2" : "=v"(wc2)
              : "v"(sacc[t][8 * ksl + 4]), "v"(sacc[t][8 * ksl + 5]));
          asm("v_cvt_pk_bf16_f32 %0, %1, %2" : "=v"(wd)
              : "v"(sacc[t][8 * ksl + 6]), "v"(sacc[t][8 * ksl + 7]));
          asm("v_permlane32_swap_b32 %0, %1" : "+v"(wa), "+v"(wc2));
          asm("v_permlane32_swap_b32 %0, %1" : "+v"(wb), "+v"(wd));
          u32x4 t4 = {wa, wb, wc2, wd};
          pa[t * 2 + ksl] = t4;
        }

#pragma unroll
      for (int ks = 0; ks < 4; ks++) {
        bf16x8 paf = __builtin_bit_cast(bf16x8, pa[ks]);
        bf16x8 bv[4];
#pragma unroll
        for (int dt = 0; dt < 4; dt++) {
          int rowv = dt * 32 + lq;
          bv[dt] = *reinterpret_cast<const bf16x8*>(
              Vc + rowv * 64 + ((((ks << 1) + hi) ^ (rowv & 7)) << 3));
        }
        __builtin_amdgcn_s_setprio(1);
#pragma unroll
        for (int dt = 0; dt < 4; dt++)
          oacc[dt] = __builtin_amdgcn_mfma_f32_32x32x16_bf16(paf, bv[dt], oacc[dt], 0, 0, 0);
        __builtin_amdgcn_s_setprio(0);
      }
    }
    SBAR(); SCHED0();
    cur ^= 1;
  }

  if (g == 0) {
    // merge heavy-tile partials (A's regs + B's scratch) and write tile qh
    const unsigned* o32 = (const unsigned*)scrO + (size_t)bid * 16384;
    float sA[16], sBv[16], li[16];
#pragma unroll
    for (int r = 0; r < 16; r++) {
      int riw = (r & 3) + 8 * (r >> 2) + 4 * hi;
      int row = 32 * w + riw;
      float mb = scrML[(size_t)bid * 512 + row];
      float lb = scrML[(size_t)bid * 512 + 256 + row];
      float ma = __shfl(mrun, riw);
      float la = __shfl(lrun, riw);
      float m = fmaxf(ma, mb);
      float aA = exp2f(ma - m), aB = exp2f(mb - m);
      sA[r] = aA; sBv[r] = aB;
      li[r] = 1.0f / (la * aA + lb * aB);
    }
#pragma unroll
    for (int dt = 0; dt < 4; dt++)
#pragma unroll
      for (int r = 0; r < 16; r += 2) {
        int rowb = 32 * w + (r & 3) + 8 * (r >> 2) + 4 * hi;
        unsigned pk = o32[(dt * 32 + lq) * 128 + (rowb >> 1)];
        float ob0 = b2f((u16)(pk & 0xffffu));
        float ob1 = b2f((u16)(pk >> 16));
        float v0 = (oacc[dt][r] * sA[r] + ob0 * sBv[r]) * li[r];
        float v1 = (oacc[dt][r + 1] * sA[r + 1] + ob1 * sBv[r + 1]) * li[r + 1];
        size_t base = ((size_t)b * S_ + (q0h + rowb)) * NQ_ + h * D_ + dt * 32 + lq;
        out[base] = f2b(v0);
        out[base + NQ_] = f2b(v1);
      }
  } else {
    // write light tile directly
    float linv = 1.0f / lrun;
#pragma unroll
    for (int r = 0; r < 16; r++) {
      const int idx_r = (r & 3) + 8 * (r >> 2) + 4 * hi;
      float lr = __shfl(linv, idx_r);
      size_t base = ((size_t)b * S_ + (q0l + 32 * w + idx_r)) * NQ_ + h * D_ + lq;
#pragma unroll
      for (int dt = 0; dt < 4; dt++)
        out[base + dt * 32] = f2b(oacc[dt][r] * lr);
    }
  }
}

extern "C" void kernel_launch(void* const* d_in, const int* in_sizes, int n_in,
                              void* d_out, int out_size, void* d_ws, size_t ws_size,
                              hipStream_t stream) {
  const float* hidden = (const float*)d_in[0];
  const float* cosp   = (const float*)d_in[1];
  const float* sinp   = (const float*)d_in[2];
  const float* q_w    = (const float*)d_in[3];
  const float* k_w    = (const float*)d_in[4];
  const float* v_w    = (const float*)d_in[5];
  const float* o_w    = (const float*)d_in[6];
  const float* qnw    = (const float*)d_in[7];
  const float* knw    = (const float*)d_in[8];

  char* p = (char*)d_ws;
  u16* hb  = (u16*)p; p += (size_t)M_ * HID_ * 2;
  u16* qwt = (u16*)p; p += (size_t)NQ_ * HID_ * 2;
  u16* kwt = (u16*)p; p += (size_t)NKV_ * HID_ * 2;
  u16* vwt = (u16*)p; p += (size_t)NKV_ * HID_ * 2;
  u16* owt = (u16*)p; p += (size_t)HID_ * NQ_ * 2;
  u16* qb  = (u16*)p; p += (size_t)B_ * H_ * S_ * D_ * 2;
  u16* kb  = (u16*)p; p += (size_t)B_ * KVH_ * S_ * D_ * 2;
  u16* vb  = (u16*)p; p += (size_t)B_ * KVH_ * S_ * D_ * 2;  // V^T [B][KVH][D][S]
  u16* ab  = (u16*)p; p += (size_t)M_ * NQ_ * 2;

  k_prep<<<6656, 256, 0, stream>>>(hidden, hb, q_w, qwt, k_w, kwt, v_w, vwt, o_w, owt);
  k_gemm_q8<<<256, 512, 0, stream>>>(hb, qwt, qb);
  k_gemm_kv<<<256, 256, 0, stream>>>(hb, kwt, vwt, kb, vb);
  k_norm_rope<<<(B_ * H_ * S_ + B_ * KVH_ * S_) / 4, 256, 0, stream>>>(qb, kb, cosp, sinp, qnw, knw);
  // attn scratch reuses qwt (O partials, 16.78MB) + kwt (m/l, 512KB) — both dead here
  k_attn<<<256, 1024, 0, stream>>>(qb, kb, vb, ab, qwt, (float*)kwt);
  k_gemm_o<<<512, 256, 0, stream>>>(ab, owt, (float*)d_out);
}

// Round 10
// 322.118 us; speedup vs baseline: 1.6364x; 1.6364x over previous
//
#include <hip/hip_runtime.h>
#include <hip/hip_bf16.h>

typedef unsigned short u16;
typedef __attribute__((ext_vector_type(4))) float f32x4;
typedef __attribute__((ext_vector_type(16))) float f32x16;
typedef __attribute__((ext_vector_type(8))) short bf16x8;
typedef __attribute__((ext_vector_type(4))) unsigned u32x4;

#define B_ 2
#define S_ 2048
#define HID_ 2048
#define H_ 32
#define KVH_ 4
#define D_ 128
#define M_ 4096
#define NQ_ 4096
#define NKV_ 512

typedef const __attribute__((address_space(1))) void gconst_void;
typedef __attribute__((address_space(3))) void lds_void;

static __device__ __forceinline__ void gload_lds16(const void* g, void* l) {
  __builtin_amdgcn_global_load_lds((gconst_void*)g, (lds_void*)l, 16, 0, 0);
}

#define WAITV(N) asm volatile("s_waitcnt vmcnt(" #N ")" ::: "memory")
#define WAITL0() asm volatile("s_waitcnt lgkmcnt(0)" ::: "memory")
#define SBAR() __builtin_amdgcn_s_barrier()
#define SCHED0() __builtin_amdgcn_sched_barrier(0)
#define CFENCE() asm volatile("" ::: "memory")

static __device__ __forceinline__ u16 f2b(float f) {
  union { float f; unsigned i; } x; x.f = f;
  return (u16)((x.i + 0x7fffu + ((x.i >> 16) & 1u)) >> 16);
}
static __device__ __forceinline__ float b2f(u16 u) {
  union { unsigned i; float f; } x; x.i = ((unsigned)u) << 16;
  return x.f;
}
static __device__ __forceinline__ float max3f(float a, float b, float c) {
  float d;
  asm("v_max3_f32 %0, %1, %2, %3" : "=v"(d) : "v"(a), "v"(b), "v"(c));
  return d;
}

// ---------------- fused prep: fp32->bf16 cvt + 4 weight transposes ----------------
static __device__ __forceinline__ void tr_tile(const float* __restrict__ W,
    u16* __restrict__ Wt, int K, int N, int n0, int k0, u16 (*t)[72]) {
  int tid = threadIdx.x;
  int r = tid >> 4;
  int c4 = (tid & 15) * 4;
#pragma unroll
  for (int i = 0; i < 4; i++) {
    int k = r + i * 16;
    float4 v = *reinterpret_cast<const float4*>(W + (size_t)(k0 + k) * N + n0 + c4);
    t[k][c4 + 0] = f2b(v.x); t[k][c4 + 1] = f2b(v.y);
    t[k][c4 + 2] = f2b(v.z); t[k][c4 + 3] = f2b(v.w);
  }
  __syncthreads();
#pragma unroll
  for (int i = 0; i < 4; i++) {
    int n = r + i * 16;
    ushort4 o;
    o.x = t[c4 + 0][n]; o.y = t[c4 + 1][n]; o.z = t[c4 + 2][n]; o.w = t[c4 + 3][n];
    *reinterpret_cast<ushort4*>(Wt + (size_t)(n0 + n) * K + k0 + c4) = o;
  }
}

__global__ __launch_bounds__(256) void k_prep(const float* __restrict__ hidden, u16* __restrict__ hb,
    const float* __restrict__ qw, u16* __restrict__ qwt,
    const float* __restrict__ kw, u16* __restrict__ kwt,
    const float* __restrict__ vw, u16* __restrict__ vwt,
    const float* __restrict__ ow, u16* __restrict__ owt) {
  __shared__ u16 t[64][72];
  const int bid = blockIdx.x;
  if (bid < 2048) {
    const int n4 = M_ * HID_ / 4;
    int i = bid * 256 + threadIdx.x;
    const int stride = 2048 * 256;
    for (; i < n4; i += stride) {
      float4 v = reinterpret_cast<const float4*>(hidden)[i];
      ushort4 o;
      o.x = f2b(v.x); o.y = f2b(v.y); o.z = f2b(v.z); o.w = f2b(v.w);
      reinterpret_cast<ushort4*>(hb)[i] = o;
    }
  } else if (bid < 4096) {
    int l = bid - 2048;
    tr_tile(qw, qwt, HID_, NQ_, (l & 63) * 64, (l >> 6) * 64, t);
  } else if (bid < 4352) {
    int l = bid - 4096;
    tr_tile(kw, kwt, HID_, NKV_, (l & 7) * 64, (l >> 3) * 64, t);
  } else if (bid < 4608) {
    int l = bid - 4352;
    tr_tile(vw, vwt, HID_, NKV_, (l & 7) * 64, (l >> 3) * 64, t);
  } else {
    int l = bid - 4608;
    tr_tile(ow, owt, NQ_, HID_, (l & 31) * 64, (l >> 5) * 64, t);
  }
}

// ---- 128x128 bf16 GEMM core, counted-vmcnt dbuf pipeline (T4) ----
__device__ __forceinline__ void gemm_core(const u16* __restrict__ A, const u16* __restrict__ Bt,
                                          int K, int m0, int n0,
                                          u16* As, u16* Bs, f32x4 (&acc)[4][4]) {
  const int tid = threadIdx.x;
  const int lane = tid & 63;
  const int wid = tid >> 6;
  const int wr = wid >> 1, wc = wid & 1;
  const int lrow = lane & 15;
  const int hi = lane >> 4;
  const f32x4 zz = {0.f, 0.f, 0.f, 0.f};
#pragma unroll
  for (int i = 0; i < 4; i++)
#pragma unroll
    for (int j = 0; j < 4; j++) acc[i][j] = zz;

  const int srow = tid >> 3;
  const int sc16 = tid & 7;
  const int nk = K >> 6;
  int cur = 0;

#pragma unroll
  for (int rep = 0; rep < 4; rep++) {
    int row = rep * 32 + srow;
    int gcol = ((sc16 ^ (row & 7)) << 3);
    gload_lds16(A + (size_t)(m0 + row) * K + gcol, As + row * 64 + sc16 * 8);
    gload_lds16(Bt + (size_t)(n0 + row) * K + gcol, Bs + row * 64 + sc16 * 8);
  }

  for (int t = 0; t < nk; t++) {
    if (t + 1 < nk) {
      int nxt = cur ^ 1;
      int kb = (t + 1) << 6;
#pragma unroll
      for (int rep = 0; rep < 4; rep++) {
        int row = rep * 32 + srow;
        int gcol = kb + ((sc16 ^ (row & 7)) << 3);
        gload_lds16(A + (size_t)(m0 + row) * K + gcol, As + nxt * 8192 + row * 64 + sc16 * 8);
        gload_lds16(Bt + (size_t)(n0 + row) * K + gcol, Bs + nxt * 8192 + row * 64 + sc16 * 8);
      }
      WAITV(8);
    } else {
      WAITV(0);
    }
    SCHED0(); SBAR(); CFENCE(); SCHED0();

    const u16* Ac = As + cur * 8192;
    const u16* Bc = Bs + cur * 8192;
#pragma unroll
    for (int kc = 0; kc < 2; kc++) {
      bf16x8 af[4], bfr[4];
#pragma unroll
      for (int i = 0; i < 4; i++) {
        int row = wr * 64 + i * 16 + lrow;
        af[i] = *reinterpret_cast<const bf16x8*>(Ac + row * 64 + ((((kc << 2) + hi) ^ (row & 7)) << 3));
      }
#pragma unroll
      for (int j = 0; j < 4; j++) {
        int row = wc * 64 + j * 16 + lrow;
        bfr[j] = *reinterpret_cast<const bf16x8*>(Bc + row * 64 + ((((kc << 2) + hi) ^ (row & 7)) << 3));
      }
#pragma unroll
      for (int i = 0; i < 4; i++)
#pragma unroll
        for (int j = 0; j < 4; j++)
          acc[i][j] = __builtin_amdgcn_mfma_f32_16x16x32_bf16(af[i], bfr[j], acc[i][j], 0, 0, 0);
    }
    SBAR(); SCHED0();
    cur ^= 1;
  }
}

// ---------------- Q projection: 256x256 4-phase template, counted vmcnt ----------------
__global__ __launch_bounds__(512, 2) void k_gemm_q8(const u16* __restrict__ A,
    const u16* __restrict__ Bt, u16* __restrict__ qb) {
  __shared__ u16 Ash[2][2][128 * 64];
  __shared__ u16 Bsh[2][2][128 * 64];
  const int bid = blockIdx.x;
  const int wg = (bid & 7) * 32 + (bid >> 3);
  const int mt = wg & 15, nt = wg >> 4;
  const int m0 = mt * 256, n0 = nt * 256;
  const int K = HID_, nk = K >> 6;
  const int tid = threadIdx.x, lane = tid & 63;
  const int wv = tid >> 6, wr = wv >> 2, wc = wv & 3;
  const int lrow = lane & 15, hi4 = lane >> 4;

  const int s0r = tid >> 3, sc = tid & 7;
  const int s1r = (tid + 512) >> 3;

  auto stgA = [&](int h, int t, int d) {
    gload_lds16(A + (size_t)(m0 + h * 128 + s0r) * K + t * 64 + ((sc ^ (s0r & 7)) << 3),
                &Ash[d][h][s0r * 64 + sc * 8]);
    gload_lds16(A + (size_t)(m0 + h * 128 + s1r) * K + t * 64 + ((sc ^ (s1r & 7)) << 3),
                &Ash[d][h][s1r * 64 + sc * 8]);
  };
  auto stgB = [&](int h, int t, int d) {
    gload_lds16(Bt + (size_t)(n0 + h * 128 + s0r) * K + t * 64 + ((sc ^ (s0r & 7)) << 3),
                &Bsh[d][h][s0r * 64 + sc * 8]);
    gload_lds16(Bt + (size_t)(n0 + h * 128 + s1r) * K + t * 64 + ((sc ^ (s1r & 7)) << 3),
                &Bsh[d][h][s1r * 64 + sc * 8]);
  };

  f32x4 acc[8][4];
  const f32x4 zz = {0.f, 0.f, 0.f, 0.f};
#pragma unroll
  for (int f = 0; f < 8; f++)
#pragma unroll
    for (int j = 0; j < 4; j++) acc[f][j] = zz;

  bf16x8 af0[4][2], af1[4][2], bfr[2][2];

  auto lda = [&](bf16x8 (&dst)[4][2], int mh, int d) {
#pragma unroll
    for (int fi = 0; fi < 4; fi++) {
      int row = fi * 32 + wr * 16 + lrow;
#pragma unroll
      for (int kk = 0; kk < 2; kk++)
        dst[fi][kk] = *reinterpret_cast<const bf16x8*>(
            &Ash[d][mh][row * 64 + ((((kk << 2) + hi4) ^ (row & 7)) << 3)]);
    }
  };
  auto ldb = [&](int nh, int d) {
#pragma unroll
    for (int ji = 0; ji < 2; ji++) {
      int row = ji * 64 + wc * 16 + lrow;
#pragma unroll
      for (int kk = 0; kk < 2; kk++)
        bfr[ji][kk] = *reinterpret_cast<const bf16x8*>(
            &Bsh[d][nh][row * 64 + ((((kk << 2) + hi4) ^ (row & 7)) << 3)]);
    }
  };
  auto mq = [&](bf16x8 (&afh)[4][2], int mh, int nh) {
    __builtin_amdgcn_s_setprio(1);
#pragma unroll
    for (int kk = 0; kk < 2; kk++)
#pragma unroll
      for (int fi = 0; fi < 4; fi++)
#pragma unroll
        for (int ji = 0; ji < 2; ji++)
          acc[mh * 4 + fi][nh * 2 + ji] = __builtin_amdgcn_mfma_f32_16x16x32_bf16(
              afh[fi][kk], bfr[ji][kk], acc[mh * 4 + fi][nh * 2 + ji], 0, 0, 0);
    __builtin_amdgcn_s_setprio(0);
  };

  stgA(0, 0, 0); stgA(1, 0, 0); stgB(0, 0, 0); stgB(1, 0, 0);
  WAITV(2); SCHED0();
  SBAR(); SCHED0();

  for (int t = 0; t < nk; t++) {
    const int d = t & 1, nd = d ^ 1;
    const bool pre = (t + 1 < nk);
    lda(af0, 0, d); ldb(0, d);
    if (pre) stgA(0, t + 1, nd);
    SCHED0(); SBAR();
    WAITL0(); SCHED0();
    mq(af0, 0, 0);
    SBAR(); SCHED0();
    lda(af1, 1, d);
    if (pre) stgA(1, t + 1, nd);
    WAITV(4); SCHED0(); SBAR();
    WAITL0(); SCHED0();
    mq(af1, 1, 0);
    SBAR(); SCHED0();
    ldb(1, d);
    if (pre) stgB(0, t + 1, nd);
    SCHED0(); SBAR();
    WAITL0(); SCHED0();
    mq(af1, 1, 1);
    SBAR(); SCHED0();
    if (pre) stgB(1, t + 1, nd);
    WAITV(2); SCHED0(); SBAR();
    mq(af0, 0, 1);
    SBAR(); SCHED0();
  }

  const int lr4 = hi4 * 4, lc = lane & 15;
#pragma unroll
  for (int f = 0; f < 8; f++)
#pragma unroll
    for (int j = 0; j < 4; j++)
#pragma unroll
      for (int rr = 0; rr < 4; rr++) {
        int m = m0 + f * 32 + wr * 16 + lr4 + rr;
        int ncol = n0 + j * 64 + wc * 16 + lc;
        int b = m >> 11, s = m & (S_ - 1);
        int head = ncol >> 7, dd = ncol & 127;
        qb[(((size_t)b * H_ + head) * S_ + s) * D_ + dd] = f2b(acc[f][j][rr]);
      }
}

// ---------------- K/V projections (128^2 core), grid 256 1D swizzled ----------------
__global__ __launch_bounds__(256, 2) void k_gemm_kv(const u16* __restrict__ hb,
    const u16* __restrict__ kwt, const u16* __restrict__ vwt,
    u16* __restrict__ kb, u16* __restrict__ vb) {
  __shared__ u16 As[2 * 128 * 64], Bs[2 * 128 * 64];
  const int bid = blockIdx.x;
  const int wg = (bid & 7) * 32 + (bid >> 3);
  const int mt = wg & 31, nt = wg >> 5;
  const bool isv = nt >= 4;
  const int head = isv ? nt - 4 : nt;
  const u16* Bt = isv ? vwt : kwt;
  f32x4 acc[4][4];
  gemm_core(hb, Bt, HID_, mt * 128, head * 128, As, Bs, acc);
  const int lane = threadIdx.x & 63;
  const int wid = threadIdx.x >> 6;
  const int wr = wid >> 1, wc = wid & 1;
  const int lr4 = (lane >> 4) * 4, lc = lane & 15;
#pragma unroll
  for (int i = 0; i < 4; i++)
#pragma unroll
    for (int j = 0; j < 4; j++)
#pragma unroll
      for (int r = 0; r < 4; r++) {
        int m = mt * 128 + wr * 64 + i * 16 + lr4 + r;
        int d = wc * 64 + j * 16 + lc;
        int b = m >> 11, s = m & (S_ - 1);
        u16 val = f2b(acc[i][j][r]);
        if (isv) vb[(((size_t)b * KVH_ + head) * D_ + d) * S_ + s] = val;  // transposed
        else     kb[(((size_t)b * KVH_ + head) * S_ + s) * D_ + d] = val;
      }
}

// ---------------- O projection (128^2 core), grid 512 1D swizzled ----------------
__global__ __launch_bounds__(256, 2) void k_gemm_o(const u16* __restrict__ ab,
    const u16* __restrict__ owt, float* __restrict__ out) {
  __shared__ u16 As[2 * 128 * 64], Bs[2 * 128 * 64];
  const int bid = blockIdx.x;
  const int wg = (bid & 7) * 64 + (bid >> 3);
  const int mt = wg & 31, nt = wg >> 5;
  f32x4 acc[4][4];
  gemm_core(ab, owt, NQ_, mt * 128, nt * 128, As, Bs, acc);
  const int lane = threadIdx.x & 63;
  const int wid = threadIdx.x >> 6;
  const int wr = wid >> 1, wc = wid & 1;
  const int lr4 = (lane >> 4) * 4, lc = lane & 15;
#pragma unroll
  for (int i = 0; i < 4; i++)
#pragma unroll
    for (int j = 0; j < 4; j++)
#pragma unroll
      for (int r = 0; r < 4; r++) {
        int m = mt * 128 + wr * 64 + i * 16 + lr4 + r;
        int n = nt * 128 + wc * 64 + j * 16 + lc;
        out[(size_t)m * HID_ + n] = acc[i][j][r];
      }
}

// ---------------- RMSNorm + RoPE; Q additionally pre-scaled by scale*log2e ----------------
__global__ __launch_bounds__(256) void k_norm_rope(u16* __restrict__ qb, u16* __restrict__ kb,
    const float* __restrict__ cosp, const float* __restrict__ sinp,
    const float* __restrict__ qnw, const float* __restrict__ knw) {
  int row = blockIdx.x * 4 + (threadIdx.x >> 6);
  int lane = threadIdx.x & 63;
  const int QROWS = B_ * H_ * S_;
  u16* ptr; const float* nw; int b, s; float os;
  if (row < QROWS) {
    ptr = qb + (size_t)row * D_; nw = qnw;
    s = row & (S_ - 1); b = row / (H_ * S_);
    os = 0.08838834764831845f * 1.44269504088896340f;
  } else {
    int r2 = row - QROWS;
    ptr = kb + (size_t)r2 * D_; nw = knw;
    s = r2 & (S_ - 1); b = r2 / (KVH_ * S_);
    os = 1.0f;
  }
  int d = lane * 2;
  float x0 = b2f(ptr[d]), x1 = b2f(ptr[d + 1]);
  float ss = x0 * x0 + x1 * x1;
#pragma unroll
  for (int m = 1; m < 64; m <<= 1) ss += __shfl_xor(ss, m);
  float inv = rsqrtf(ss * (1.0f / 128.0f) + 1e-6f) * os;
  x0 = x0 * inv * nw[d]; x1 = x1 * inv * nw[d + 1];
  float p0 = __shfl_xor(x0, 32), p1 = __shfl_xor(x1, 32);
  float r0 = (lane < 32) ? -p0 : p0;
  float r1 = (lane < 32) ? -p1 : p1;
  const float* cp = cosp + ((size_t)b * S_ + s) * D_;
  const float* sp = sinp + ((size_t)b * S_ + s) * D_;
  ptr[d]     = f2b(x0 * cp[d]     + r0 * sp[d]);
  ptr[d + 1] = f2b(x1 * cp[d + 1] + r1 * sp[d + 1]);
}

// ------ causal GQA flash attention: 4-warp blocks, q-tile 128, paired {qx,15-qx} ------
// grid 512 (XCD-swizzled) = 2 blocks/CU (LDS 64KB). Every block: 34 kv-iters
// (deterministic balance within block). Counted-vmcnt dbuf pipeline; swapped QK^T;
// in-register softmax (exp2 domain, Q pre-scaled); cvt_pk+permlane P->A-frags.
__global__ __launch_bounds__(256, 2) void k_attn(const u16* __restrict__ q,
    const u16* __restrict__ k, const u16* __restrict__ vt, u16* __restrict__ out) {
  __shared__ u16 Kb[2 * 64 * 128];   // [dbuf][kv 64][d 128], 16 slots/row, slot ^= row&15
  __shared__ u16 Vb[2 * 128 * 64];   // [dbuf][d 128][kv 64],  8 slots/row, slot ^= row&7
  const int bid = blockIdx.x;
  const int wg = (bid & 7) * 64 + (bid >> 3);
  const int qx = wg & 7, bh = wg >> 3;
  const int b = bh >> 5, h = bh & 31;
  const int kvh = h >> 3;
  const int tid = threadIdx.x, lane = tid & 63, w = tid >> 6;   // w in 0..3
  const int lq = lane & 31, hi = lane >> 5;
  const u16* qp  = q  + ((size_t)(b * H_ + h) * S_) * D_;
  const u16* kp  = k  + ((size_t)(b * KVH_ + kvh) * S_) * D_;
  const u16* vtp = vt + ((size_t)(b * KVH_ + kvh) * D_) * S_;

  // staging (256 threads, 4 passes each for K and V)
  const int rowKa = tid >> 4;                          // 0..15 (+16p)
  const int colK  = ((tid & 15) ^ (rowKa & 15)) << 3;  // row&15 invariant under +16
  const int rowVa = tid >> 3;                          // 0..31 (+32p)
  const int colV  = ((tid & 7) ^ (rowVa & 7)) << 3;    // row&7 invariant under +32

  auto stage = [&](int n0, int cu) {
    u16* kd = Kb + cu * 8192 + tid * 8;
    u16* vd = Vb + cu * 8192 + tid * 8;
#pragma unroll
    for (int p = 0; p < 4; p++)
      gload_lds16(kp + (size_t)(n0 + p * 16 + rowKa) * D_ + colK, kd + p * 2048);
#pragma unroll
    for (int p = 0; p < 4; p++)
      gload_lds16(vtp + (size_t)(p * 32 + rowVa) * S_ + n0 + colV, vd + p * 2048);
  };

  const f32x16 z16 = {0.f};
  int cur = 0;

  for (int half = 0; half < 2; half++) {
    const int qt = half ? (15 - qx) : qx;
    const int q0 = qt * 128;
    const int last = 2 * qt + 1;
    const int qg = q0 + 32 * w + lq;

    stage(0, cur);

    bf16x8 qf[8];
#pragma unroll
    for (int ds = 0; ds < 8; ds++)
      qf[ds] = *reinterpret_cast<const bf16x8*>(qp + (size_t)qg * D_ + ds * 16 + hi * 8);

    f32x16 oacc[4];
#pragma unroll
    for (int dt = 0; dt < 4; dt++) oacc[dt] = z16;
    float mrun = -1e30f, lrun = 0.f;

    for (int nt = 0; nt <= last; nt++) {
      const int n0 = nt * 64;
      if (nt < last) {
        stage(n0 + 64, cur ^ 1);
        WAITV(8);   // drain tile nt's 8 loads; keep nt+1's in flight
      } else {
        WAITV(0);
      }
      SCHED0(); SBAR(); CFENCE(); SCHED0();

      const u16* Kc = Kb + cur * 8192;
      const u16* Vc = Vb + cur * 8192;

      const bool skip = (n0 > q0 + 32 * w + 31);
      if (!skip) {
        const bool needmask = (n0 + 63 > q0 + 32 * w);

        f32x16 sacc[2];
        sacc[0] = z16; sacc[1] = z16;
#pragma unroll
        for (int ds = 0; ds < 8; ds++) {
          const int sl = (((ds << 1) + hi) ^ (lq & 15)) << 3;
          bf16x8 ka0 = *reinterpret_cast<const bf16x8*>(Kc + lq * 128 + sl);
          bf16x8 ka1 = *reinterpret_cast<const bf16x8*>(Kc + (lq + 32) * 128 + sl);
          __builtin_amdgcn_s_setprio(1);
          sacc[0] = __builtin_amdgcn_mfma_f32_32x32x16_bf16(ka0, qf[ds], sacc[0], 0, 0, 0);
          sacc[1] = __builtin_amdgcn_mfma_f32_32x32x16_bf16(ka1, qf[ds], sacc[1], 0, 0, 0);
          __builtin_amdgcn_s_setprio(0);
        }

        if (needmask) {
#pragma unroll
          for (int t = 0; t < 2; t++)
#pragma unroll
            for (int r = 0; r < 16; r++) {
              int kvg = n0 + 32 * t + (r & 3) + 8 * (r >> 2) + 4 * hi;
              if (kvg > qg) sacc[t][r] = -1e30f;
            }
        }
        float tm = fmaxf(sacc[0][0], sacc[0][1]);
#pragma unroll
        for (int i = 1; i < 16; i++) {
          const int e0 = 2 * i, e1 = 2 * i + 1;
          tm = max3f(tm, sacc[e0 >> 4][e0 & 15], sacc[e1 >> 4][e1 & 15]);
        }
        tm = fmaxf(tm, __shfl_xor(tm, 32));
        if (__any(tm > mrun + 8.f)) {   // defer-max (T13), log2 units
          float mn = fmaxf(mrun, tm);
          float al = exp2f(mrun - mn);
          mrun = mn;
          lrun *= al;
#pragma unroll
          for (int r = 0; r < 16; r++) {
            float ar = __shfl(al, (r & 3) + 8 * (r >> 2) + 4 * hi);
#pragma unroll
            for (int dt = 0; dt < 4; dt++) oacc[dt][r] *= ar;
          }
        }
        float rs = 0.f;
#pragma unroll
        for (int t = 0; t < 2; t++)
#pragma unroll
          for (int r = 0; r < 16; r++) {
            float pv = exp2f(sacc[t][r] - mrun);
            sacc[t][r] = pv;
            rs += pv;
          }
        rs += __shfl_xor(rs, 32);
        lrun += rs;

        u32x4 pa[4];
#pragma unroll
        for (int t = 0; t < 2; t++)
#pragma unroll
          for (int ksl = 0; ksl < 2; ksl++) {
            unsigned wa, wb, wc2, wd;
            asm("v_cvt_pk_bf16_f32 %0, %1, %2" : "=v"(wa)
                : "v"(sacc[t][8 * ksl + 0]), "v"(sacc[t][8 * ksl + 1]));
            asm("v_cvt_pk_bf16_f32 %0, %1, %2" : "=v"(wb)
                : "v"(sacc[t][8 * ksl + 2]), "v"(sacc[t][8 * ksl + 3]));
            asm("v_cvt_pk_bf16_f32 %0, %1, %2" : "=v"(wc2)
                : "v"(sacc[t][8 * ksl + 4]), "v"(sacc[t][8 * ksl + 5]));
            asm("v_cvt_pk_bf16_f32 %0, %1, %2" : "=v"(wd)
                : "v"(sacc[t][8 * ksl + 6]), "v"(sacc[t][8 * ksl + 7]));
            asm("v_permlane32_swap_b32 %0, %1" : "+v"(wa), "+v"(wc2));
            asm("v_permlane32_swap_b32 %0, %1" : "+v"(wb), "+v"(wd));
            u32x4 t4 = {wa, wb, wc2, wd};
            pa[t * 2 + ksl] = t4;
          }

#pragma unroll
        for (int ks = 0; ks < 4; ks++) {
          bf16x8 paf = __builtin_bit_cast(bf16x8, pa[ks]);
          bf16x8 bv[4];
#pragma unroll
          for (int dt = 0; dt < 4; dt++) {
            int rowv = dt * 32 + lq;
            bv[dt] = *reinterpret_cast<const bf16x8*>(
                Vc + rowv * 64 + ((((ks << 1) + hi) ^ (rowv & 7)) << 3));
          }
          __builtin_amdgcn_s_setprio(1);
#pragma unroll
          for (int dt = 0; dt < 4; dt++)
            oacc[dt] = __builtin_amdgcn_mfma_f32_32x32x16_bf16(paf, bv[dt], oacc[dt], 0, 0, 0);
          __builtin_amdgcn_s_setprio(0);
        }
      }
      SBAR(); SCHED0();
      cur ^= 1;
    }

    float linv = 1.0f / lrun;
#pragma unroll
    for (int r = 0; r < 16; r++) {
      const int idx_r = (r & 3) + 8 * (r >> 2) + 4 * hi;
      float lr = __shfl(linv, idx_r);
      size_t base = ((size_t)b * S_ + (q0 + 32 * w + idx_r)) * NQ_ + h * D_ + lq;
#pragma unroll
      for (int dt = 0; dt < 4; dt++)
        out[base + dt * 32] = f2b(oacc[dt][r] * lr);
    }
  }
}

extern "C" void kernel_launch(void* const* d_in, const int* in_sizes, int n_in,
                              void* d_out, int out_size, void* d_ws, size_t ws_size,
                              hipStream_t stream) {
  const float* hidden = (const float*)d_in[0];
  const float* cosp   = (const float*)d_in[1];
  const float* sinp   = (const float*)d_in[2];
  const float* q_w    = (const float*)d_in[3];
  const float* k_w    = (const float*)d_in[4];
  const float* v_w    = (const float*)d_in[5];
  const float* o_w    = (const float*)d_in[6];
  const float* qnw    = (const float*)d_in[7];
  const float* knw    = (const float*)d_in[8];

  char* p = (char*)d_ws;
  u16* hb  = (u16*)p; p += (size_t)M_ * HID_ * 2;
  u16* qwt = (u16*)p; p += (size_t)NQ_ * HID_ * 2;
  u16* kwt = (u16*)p; p += (size_t)NKV_ * HID_ * 2;
  u16* vwt = (u16*)p; p += (size_t)NKV_ * HID_ * 2;
  u16* owt = (u16*)p; p += (size_t)HID_ * NQ_ * 2;
  u16* qb  = (u16*)p; p += (size_t)B_ * H_ * S_ * D_ * 2;
  u16* kb  = (u16*)p; p += (size_t)B_ * KVH_ * S_ * D_ * 2;
  u16* vb  = (u16*)p; p += (size_t)B_ * KVH_ * S_ * D_ * 2;  // V^T [B][KVH][D][S]
  u16* ab  = (u16*)p; p += (size_t)M_ * NQ_ * 2;

  k_prep<<<6656, 256, 0, stream>>>(hidden, hb, q_w, qwt, k_w, kwt, v_w, vwt, o_w, owt);
  k_gemm_q8<<<256, 512, 0, stream>>>(hb, qwt, qb);
  k_gemm_kv<<<256, 256, 0, stream>>>(hb, kwt, vwt, kb, vb);
  k_norm_rope<<<(B_ * H_ * S_ + B_ * KVH_ * S_) / 4, 256, 0, stream>>>(qb, kb, cosp, sinp, qnw, knw);
  k_attn<<<512, 256, 0, stream>>>(qb, kb, vb, ab);
  k_gemm_o<<<512, 256, 0, stream>>>(ab, owt, (float*)d_out);
}

// Round 11
// 319.011 us; speedup vs baseline: 1.6524x; 1.0097x over previous
//
#include <hip/hip_runtime.h>
#include <hip/hip_bf16.h>

typedef unsigned short u16;
typedef __attribute__((ext_vector_type(4))) float f32x4;
typedef __attribute__((ext_vector_type(16))) float f32x16;
typedef __attribute__((ext_vector_type(8))) short bf16x8;
typedef __attribute__((ext_vector_type(4))) unsigned u32x4;

#define B_ 2
#define S_ 2048
#define HID_ 2048
#define H_ 32
#define KVH_ 4
#define D_ 128
#define M_ 4096
#define NQ_ 4096
#define NKV_ 512

typedef const __attribute__((address_space(1))) void gconst_void;
typedef __attribute__((address_space(3))) void lds_void;

static __device__ __forceinline__ void gload_lds16(const void* g, void* l) {
  __builtin_amdgcn_global_load_lds((gconst_void*)g, (lds_void*)l, 16, 0, 0);
}

#define WAITV(N) asm volatile("s_waitcnt vmcnt(" #N ")" ::: "memory")
#define WAITL0() asm volatile("s_waitcnt lgkmcnt(0)" ::: "memory")
#define SBAR() __builtin_amdgcn_s_barrier()
#define SCHED0() __builtin_amdgcn_sched_barrier(0)
#define CFENCE() asm volatile("" ::: "memory")

static __device__ __forceinline__ u16 f2b(float f) {
  union { float f; unsigned i; } x; x.f = f;
  return (u16)((x.i + 0x7fffu + ((x.i >> 16) & 1u)) >> 16);
}
static __device__ __forceinline__ float b2f(u16 u) {
  union { unsigned i; float f; } x; x.i = ((unsigned)u) << 16;
  return x.f;
}
static __device__ __forceinline__ float max3f(float a, float b, float c) {
  float d;
  asm("v_max3_f32 %0, %1, %2, %3" : "=v"(d) : "v"(a), "v"(b), "v"(c));
  return d;
}

// ---------------- fused prep: fp32->bf16 cvt + 4 weight transposes ----------------
static __device__ __forceinline__ void tr_tile(const float* __restrict__ W,
    u16* __restrict__ Wt, int K, int N, int n0, int k0, u16 (*t)[72]) {
  int tid = threadIdx.x;
  int r = tid >> 4;
  int c4 = (tid & 15) * 4;
#pragma unroll
  for (int i = 0; i < 4; i++) {
    int k = r + i * 16;
    float4 v = *reinterpret_cast<const float4*>(W + (size_t)(k0 + k) * N + n0 + c4);
    t[k][c4 + 0] = f2b(v.x); t[k][c4 + 1] = f2b(v.y);
    t[k][c4 + 2] = f2b(v.z); t[k][c4 + 3] = f2b(v.w);
  }
  __syncthreads();
#pragma unroll
  for (int i = 0; i < 4; i++) {
    int n = r + i * 16;
    ushort4 o;
    o.x = t[c4 + 0][n]; o.y = t[c4 + 1][n]; o.z = t[c4 + 2][n]; o.w = t[c4 + 3][n];
    *reinterpret_cast<ushort4*>(Wt + (size_t)(n0 + n) * K + k0 + c4) = o;
  }
}

__global__ __launch_bounds__(256) void k_prep(const float* __restrict__ hidden, u16* __restrict__ hb,
    const float* __restrict__ qw, u16* __restrict__ qwt,
    const float* __restrict__ kw, u16* __restrict__ kwt,
    const float* __restrict__ vw, u16* __restrict__ vwt,
    const float* __restrict__ ow, u16* __restrict__ owt) {
  __shared__ u16 t[64][72];
  const int bid = blockIdx.x;
  if (bid < 2048) {
    const int n4 = M_ * HID_ / 4;
    int i = bid * 256 + threadIdx.x;
    const int stride = 2048 * 256;
    for (; i < n4; i += stride) {
      float4 v = reinterpret_cast<const float4*>(hidden)[i];
      ushort4 o;
      o.x = f2b(v.x); o.y = f2b(v.y); o.z = f2b(v.z); o.w = f2b(v.w);
      reinterpret_cast<ushort4*>(hb)[i] = o;
    }
  } else if (bid < 4096) {
    int l = bid - 2048;
    tr_tile(qw, qwt, HID_, NQ_, (l & 63) * 64, (l >> 6) * 64, t);
  } else if (bid < 4352) {
    int l = bid - 4096;
    tr_tile(kw, kwt, HID_, NKV_, (l & 7) * 64, (l >> 3) * 64, t);
  } else if (bid < 4608) {
    int l = bid - 4352;
    tr_tile(vw, vwt, HID_, NKV_, (l & 7) * 64, (l >> 3) * 64, t);
  } else {
    int l = bid - 4608;
    tr_tile(ow, owt, NQ_, HID_, (l & 31) * 64, (l >> 5) * 64, t);
  }
}

// ---- 128x128 bf16 GEMM core, counted-vmcnt dbuf pipeline (T4) ----
__device__ __forceinline__ void gemm_core(const u16* __restrict__ A, const u16* __restrict__ Bt,
                                          int K, int m0, int n0,
                                          u16* As, u16* Bs, f32x4 (&acc)[4][4]) {
  const int tid = threadIdx.x;
  const int lane = tid & 63;
  const int wid = tid >> 6;
  const int wr = wid >> 1, wc = wid & 1;
  const int lrow = lane & 15;
  const int hi = lane >> 4;
  const f32x4 zz = {0.f, 0.f, 0.f, 0.f};
#pragma unroll
  for (int i = 0; i < 4; i++)
#pragma unroll
    for (int j = 0; j < 4; j++) acc[i][j] = zz;

  const int srow = tid >> 3;
  const int sc16 = tid & 7;
  const int nk = K >> 6;
  int cur = 0;

#pragma unroll
  for (int rep = 0; rep < 4; rep++) {
    int row = rep * 32 + srow;
    int gcol = ((sc16 ^ (row & 7)) << 3);
    gload_lds16(A + (size_t)(m0 + row) * K + gcol, As + row * 64 + sc16 * 8);
    gload_lds16(Bt + (size_t)(n0 + row) * K + gcol, Bs + row * 64 + sc16 * 8);
  }

  for (int t = 0; t < nk; t++) {
    if (t + 1 < nk) {
      int nxt = cur ^ 1;
      int kb = (t + 1) << 6;
#pragma unroll
      for (int rep = 0; rep < 4; rep++) {
        int row = rep * 32 + srow;
        int gcol = kb + ((sc16 ^ (row & 7)) << 3);
        gload_lds16(A + (size_t)(m0 + row) * K + gcol, As + nxt * 8192 + row * 64 + sc16 * 8);
        gload_lds16(Bt + (size_t)(n0 + row) * K + gcol, Bs + nxt * 8192 + row * 64 + sc16 * 8);
      }
      WAITV(8);
    } else {
      WAITV(0);
    }
    SCHED0(); SBAR(); CFENCE(); SCHED0();

    const u16* Ac = As + cur * 8192;
    const u16* Bc = Bs + cur * 8192;
#pragma unroll
    for (int kc = 0; kc < 2; kc++) {
      bf16x8 af[4], bfr[4];
#pragma unroll
      for (int i = 0; i < 4; i++) {
        int row = wr * 64 + i * 16 + lrow;
        af[i] = *reinterpret_cast<const bf16x8*>(Ac + row * 64 + ((((kc << 2) + hi) ^ (row & 7)) << 3));
      }
#pragma unroll
      for (int j = 0; j < 4; j++) {
        int row = wc * 64 + j * 16 + lrow;
        bfr[j] = *reinterpret_cast<const bf16x8*>(Bc + row * 64 + ((((kc << 2) + hi) ^ (row & 7)) << 3));
      }
#pragma unroll
      for (int i = 0; i < 4; i++)
#pragma unroll
        for (int j = 0; j < 4; j++)
          acc[i][j] = __builtin_amdgcn_mfma_f32_16x16x32_bf16(af[i], bfr[j], acc[i][j], 0, 0, 0);
    }
    SBAR(); SCHED0();
    cur ^= 1;
  }
}

// ---------------- Q projection: 256x256 4-phase template, counted vmcnt ----------------
__global__ __launch_bounds__(512, 2) void k_gemm_q8(const u16* __restrict__ A,
    const u16* __restrict__ Bt, u16* __restrict__ qb) {
  __shared__ u16 Ash[2][2][128 * 64];
  __shared__ u16 Bsh[2][2][128 * 64];
  const int bid = blockIdx.x;
  const int wg = (bid & 7) * 32 + (bid >> 3);
  const int mt = wg & 15, nt = wg >> 4;
  const int m0 = mt * 256, n0 = nt * 256;
  const int K = HID_, nk = K >> 6;
  const int tid = threadIdx.x, lane = tid & 63;
  const int wv = tid >> 6, wr = wv >> 2, wc = wv & 3;
  const int lrow = lane & 15, hi4 = lane >> 4;

  const int s0r = tid >> 3, sc = tid & 7;
  const int s1r = (tid + 512) >> 3;

  auto stgA = [&](int h, int t, int d) {
    gload_lds16(A + (size_t)(m0 + h * 128 + s0r) * K + t * 64 + ((sc ^ (s0r & 7)) << 3),
                &Ash[d][h][s0r * 64 + sc * 8]);
    gload_lds16(A + (size_t)(m0 + h * 128 + s1r) * K + t * 64 + ((sc ^ (s1r & 7)) << 3),
                &Ash[d][h][s1r * 64 + sc * 8]);
  };
  auto stgB = [&](int h, int t, int d) {
    gload_lds16(Bt + (size_t)(n0 + h * 128 + s0r) * K + t * 64 + ((sc ^ (s0r & 7)) << 3),
                &Bsh[d][h][s0r * 64 + sc * 8]);
    gload_lds16(Bt + (size_t)(n0 + h * 128 + s1r) * K + t * 64 + ((sc ^ (s1r & 7)) << 3),
                &Bsh[d][h][s1r * 64 + sc * 8]);
  };

  f32x4 acc[8][4];
  const f32x4 zz = {0.f, 0.f, 0.f, 0.f};
#pragma unroll
  for (int f = 0; f < 8; f++)
#pragma unroll
    for (int j = 0; j < 4; j++) acc[f][j] = zz;

  bf16x8 af0[4][2], af1[4][2], bfr[2][2];

  auto lda = [&](bf16x8 (&dst)[4][2], int mh, int d) {
#pragma unroll
    for (int fi = 0; fi < 4; fi++) {
      int row = fi * 32 + wr * 16 + lrow;
#pragma unroll
      for (int kk = 0; kk < 2; kk++)
        dst[fi][kk] = *reinterpret_cast<const bf16x8*>(
            &Ash[d][mh][row * 64 + ((((kk << 2) + hi4) ^ (row & 7)) << 3)]);
    }
  };
  auto ldb = [&](int nh, int d) {
#pragma unroll
    for (int ji = 0; ji < 2; ji++) {
      int row = ji * 64 + wc * 16 + lrow;
#pragma unroll
      for (int kk = 0; kk < 2; kk++)
        bfr[ji][kk] = *reinterpret_cast<const bf16x8*>(
            &Bsh[d][nh][row * 64 + ((((kk << 2) + hi4) ^ (row & 7)) << 3)]);
    }
  };
  auto mq = [&](bf16x8 (&afh)[4][2], int mh, int nh) {
    __builtin_amdgcn_s_setprio(1);
#pragma unroll
    for (int kk = 0; kk < 2; kk++)
#pragma unroll
      for (int fi = 0; fi < 4; fi++)
#pragma unroll
        for (int ji = 0; ji < 2; ji++)
          acc[mh * 4 + fi][nh * 2 + ji] = __builtin_amdgcn_mfma_f32_16x16x32_bf16(
              afh[fi][kk], bfr[ji][kk], acc[mh * 4 + fi][nh * 2 + ji], 0, 0, 0);
    __builtin_amdgcn_s_setprio(0);
  };

  stgA(0, 0, 0); stgA(1, 0, 0); stgB(0, 0, 0); stgB(1, 0, 0);
  WAITV(2); SCHED0();
  SBAR(); SCHED0();

  for (int t = 0; t < nk; t++) {
    const int d = t & 1, nd = d ^ 1;
    const bool pre = (t + 1 < nk);
    lda(af0, 0, d); ldb(0, d);
    if (pre) stgA(0, t + 1, nd);
    SCHED0(); SBAR();
    WAITL0(); SCHED0();
    mq(af0, 0, 0);
    SBAR(); SCHED0();
    lda(af1, 1, d);
    if (pre) stgA(1, t + 1, nd);
    WAITV(4); SCHED0(); SBAR();
    WAITL0(); SCHED0();
    mq(af1, 1, 0);
    SBAR(); SCHED0();
    ldb(1, d);
    if (pre) stgB(0, t + 1, nd);
    SCHED0(); SBAR();
    WAITL0(); SCHED0();
    mq(af1, 1, 1);
    SBAR(); SCHED0();
    if (pre) stgB(1, t + 1, nd);
    WAITV(2); SCHED0(); SBAR();
    mq(af0, 0, 1);
    SBAR(); SCHED0();
  }

  const int lr4 = hi4 * 4, lc = lane & 15;
#pragma unroll
  for (int f = 0; f < 8; f++)
#pragma unroll
    for (int j = 0; j < 4; j++)
#pragma unroll
      for (int rr = 0; rr < 4; rr++) {
        int m = m0 + f * 32 + wr * 16 + lr4 + rr;
        int ncol = n0 + j * 64 + wc * 16 + lc;
        int b = m >> 11, s = m & (S_ - 1);
        int head = ncol >> 7, dd = ncol & 127;
        qb[(((size_t)b * H_ + head) * S_ + s) * D_ + dd] = f2b(acc[f][j][rr]);
      }
}

// ---------------- K/V projections (128^2 core), grid 256 1D swizzled ----------------
__global__ __launch_bounds__(256, 2) void k_gemm_kv(const u16* __restrict__ hb,
    const u16* __restrict__ kwt, const u16* __restrict__ vwt,
    u16* __restrict__ kb, u16* __restrict__ vb) {
  __shared__ u16 As[2 * 128 * 64], Bs[2 * 128 * 64];
  const int bid = blockIdx.x;
  const int wg = (bid & 7) * 32 + (bid >> 3);
  const int mt = wg & 31, nt = wg >> 5;
  const bool isv = nt >= 4;
  const int head = isv ? nt - 4 : nt;
  const u16* Bt = isv ? vwt : kwt;
  f32x4 acc[4][4];
  gemm_core(hb, Bt, HID_, mt * 128, head * 128, As, Bs, acc);
  const int lane = threadIdx.x & 63;
  const int wid = threadIdx.x >> 6;
  const int wr = wid >> 1, wc = wid & 1;
  const int lr4 = (lane >> 4) * 4, lc = lane & 15;
#pragma unroll
  for (int i = 0; i < 4; i++)
#pragma unroll
    for (int j = 0; j < 4; j++)
#pragma unroll
      for (int r = 0; r < 4; r++) {
        int m = mt * 128 + wr * 64 + i * 16 + lr4 + r;
        int d = wc * 64 + j * 16 + lc;
        int b = m >> 11, s = m & (S_ - 1);
        u16 val = f2b(acc[i][j][r]);
        if (isv) vb[(((size_t)b * KVH_ + head) * D_ + d) * S_ + s] = val;  // transposed
        else     kb[(((size_t)b * KVH_ + head) * S_ + s) * D_ + d] = val;
      }
}

// ---------------- O projection (128^2 core), grid 512 1D swizzled ----------------
__global__ __launch_bounds__(256, 2) void k_gemm_o(const u16* __restrict__ ab,
    const u16* __restrict__ owt, float* __restrict__ out) {
  __shared__ u16 As[2 * 128 * 64], Bs[2 * 128 * 64];
  const int bid = blockIdx.x;
  const int wg = (bid & 7) * 64 + (bid >> 3);
  const int mt = wg & 31, nt = wg >> 5;
  f32x4 acc[4][4];
  gemm_core(ab, owt, NQ_, mt * 128, nt * 128, As, Bs, acc);
  const int lane = threadIdx.x & 63;
  const int wid = threadIdx.x >> 6;
  const int wr = wid >> 1, wc = wid & 1;
  const int lr4 = (lane >> 4) * 4, lc = lane & 15;
#pragma unroll
  for (int i = 0; i < 4; i++)
#pragma unroll
    for (int j = 0; j < 4; j++)
#pragma unroll
      for (int r = 0; r < 4; r++) {
        int m = mt * 128 + wr * 64 + i * 16 + lr4 + r;
        int n = nt * 128 + wc * 64 + j * 16 + lc;
        out[(size_t)m * HID_ + n] = acc[i][j][r];
      }
}

// ---------------- RMSNorm + RoPE; Q additionally pre-scaled by scale*log2e ----------------
__global__ __launch_bounds__(256) void k_norm_rope(u16* __restrict__ qb, u16* __restrict__ kb,
    const float* __restrict__ cosp, const float* __restrict__ sinp,
    const float* __restrict__ qnw, const float* __restrict__ knw) {
  int row = blockIdx.x * 4 + (threadIdx.x >> 6);
  int lane = threadIdx.x & 63;
  const int QROWS = B_ * H_ * S_;
  u16* ptr; const float* nw; int b, s; float os;
  if (row < QROWS) {
    ptr = qb + (size_t)row * D_; nw = qnw;
    s = row & (S_ - 1); b = row / (H_ * S_);
    os = 0.08838834764831845f * 1.44269504088896340f;
  } else {
    int r2 = row - QROWS;
    ptr = kb + (size_t)r2 * D_; nw = knw;
    s = r2 & (S_ - 1); b = r2 / (KVH_ * S_);
    os = 1.0f;
  }
  int d = lane * 2;
  float x0 = b2f(ptr[d]), x1 = b2f(ptr[d + 1]);
  float ss = x0 * x0 + x1 * x1;
#pragma unroll
  for (int m = 1; m < 64; m <<= 1) ss += __shfl_xor(ss, m);
  float inv = rsqrtf(ss * (1.0f / 128.0f) + 1e-6f) * os;
  x0 = x0 * inv * nw[d]; x1 = x1 * inv * nw[d + 1];
  float p0 = __shfl_xor(x0, 32), p1 = __shfl_xor(x1, 32);
  float r0 = (lane < 32) ? -p0 : p0;
  float r1 = (lane < 32) ? -p1 : p1;
  const float* cp = cosp + ((size_t)b * S_ + s) * D_;
  const float* sp = sinp + ((size_t)b * S_ + s) * D_;
  ptr[d]     = f2b(x0 * cp[d]     + r0 * sp[d]);
  ptr[d + 1] = f2b(x1 * cp[d + 1] + r1 * sp[d + 1]);
}

// ------ causal GQA flash attention: 4-warp blocks, q-tile 128, paired {qx,15-qx} ------
// grid 512 (XCD-swizzled). LDS 48KB (K dbuf 32KB + V single 16KB) -> 3 blocks/CU,
// 12 waves/CU. Counted-vmcnt: per iter {issue K(nt+1); WAITV(8)=drain K(nt); bar;
// QK^T+softmax; WAITV(4)=drain V(nt); bar; PV; bar; issue V(nt+1)}.
__global__ __launch_bounds__(256, 2) void k_attn(const u16* __restrict__ q,
    const u16* __restrict__ k, const u16* __restrict__ vt, u16* __restrict__ out) {
  __shared__ u16 Kb[2 * 64 * 128];   // [dbuf][kv 64][d 128], 16 slots/row, slot ^= row&15
  __shared__ u16 Vb[128 * 64];       // [d 128][kv 64], 8 slots/row, slot ^= row&7
  const int bid = blockIdx.x;
  const int wg = (bid & 7) * 64 + (bid >> 3);
  const int qx = wg & 7, bh = wg >> 3;
  const int b = bh >> 5, h = bh & 31;
  const int kvh = h >> 3;
  const int tid = threadIdx.x, lane = tid & 63, w = tid >> 6;   // w in 0..3
  const int lq = lane & 31, hi = lane >> 5;
  const u16* qp  = q  + ((size_t)(b * H_ + h) * S_) * D_;
  const u16* kp  = k  + ((size_t)(b * KVH_ + kvh) * S_) * D_;
  const u16* vtp = vt + ((size_t)(b * KVH_ + kvh) * D_) * S_;

  const int rowKa = tid >> 4;                          // 0..15 (+16p)
  const int colK  = ((tid & 15) ^ (rowKa & 15)) << 3;
  const int rowVa = tid >> 3;                          // 0..31 (+32p)
  const int colV  = ((tid & 7) ^ (rowVa & 7)) << 3;

  auto stageK = [&](int n0, int cu) {
    u16* kd = Kb + cu * 8192 + tid * 8;
#pragma unroll
    for (int p = 0; p < 4; p++)
      gload_lds16(kp + (size_t)(n0 + p * 16 + rowKa) * D_ + colK, kd + p * 2048);
  };
  auto stageV = [&](int n0) {
    u16* vd = Vb + tid * 8;
#pragma unroll
    for (int p = 0; p < 4; p++)
      gload_lds16(vtp + (size_t)(p * 32 + rowVa) * S_ + n0 + colV, vd + p * 2048);
  };

  const f32x16 z16 = {0.f};
  int cur = 0;

  for (int half = 0; half < 2; half++) {
    const int qt = half ? (15 - qx) : qx;
    const int q0 = qt * 128;
    const int last = 2 * qt + 1;
    const int qg = q0 + 32 * w + lq;

    SBAR(); SCHED0();          // previous half fully done with Kb/Vb
    stageK(0, cur);            // K(0): 4 loads/thread
    stageV(0);                 // V(0): 4 loads/thread

    bf16x8 qf[8];
#pragma unroll
    for (int ds = 0; ds < 8; ds++)
      qf[ds] = *reinterpret_cast<const bf16x8*>(qp + (size_t)qg * D_ + ds * 16 + hi * 8);

    f32x16 oacc[4];
#pragma unroll
    for (int dt = 0; dt < 4; dt++) oacc[dt] = z16;
    float mrun = -1e30f, lrun = 0.f;

    for (int nt = 0; nt <= last; nt++) {
      const int n0 = nt * 64;
      // invariant at top: outstanding = K(nt):4 + V(nt):4
      if (nt < last) {
        stageK(n0 + 64, cur ^ 1);   // +4 -> 12 outstanding
        WAITV(8);                   // drain exactly K(nt)
      } else {
        WAITV(4);                   // drain K(last), keep V(last)
      }
      SCHED0(); SBAR(); CFENCE(); SCHED0();

      const u16* Kc = Kb + cur * 8192;
      const bool skip = (n0 > q0 + 32 * w + 31);

      f32x16 sacc[2];
      if (!skip) {
        const bool needmask = (n0 + 63 > q0 + 32 * w);

        sacc[0] = z16; sacc[1] = z16;
#pragma unroll
        for (int ds = 0; ds < 8; ds++) {
          const int sl = (((ds << 1) + hi) ^ (lq & 15)) << 3;
          bf16x8 ka0 = *reinterpret_cast<const bf16x8*>(Kc + lq * 128 + sl);
          bf16x8 ka1 = *reinterpret_cast<const bf16x8*>(Kc + (lq + 32) * 128 + sl);
          __builtin_amdgcn_s_setprio(1);
          sacc[0] = __builtin_amdgcn_mfma_f32_32x32x16_bf16(ka0, qf[ds], sacc[0], 0, 0, 0);
          sacc[1] = __builtin_amdgcn_mfma_f32_32x32x16_bf16(ka1, qf[ds], sacc[1], 0, 0, 0);
          __builtin_amdgcn_s_setprio(0);
        }

        if (needmask) {
#pragma unroll
          for (int t = 0; t < 2; t++)
#pragma unroll
            for (int r = 0; r < 16; r++) {
              int kvg = n0 + 32 * t + (r & 3) + 8 * (r >> 2) + 4 * hi;
              if (kvg > qg) sacc[t][r] = -1e30f;
            }
        }
        float tm = fmaxf(sacc[0][0], sacc[0][1]);
#pragma unroll
        for (int i = 1; i < 16; i++) {
          const int e0 = 2 * i, e1 = 2 * i + 1;
          tm = max3f(tm, sacc[e0 >> 4][e0 & 15], sacc[e1 >> 4][e1 & 15]);
        }
        tm = fmaxf(tm, __shfl_xor(tm, 32));
        if (__any(tm > mrun + 8.f)) {   // defer-max (T13), log2 units
          float mn = fmaxf(mrun, tm);
          float al = exp2f(mrun - mn);
          mrun = mn;
          lrun *= al;
#pragma unroll
          for (int r = 0; r < 16; r++) {
            float ar = __shfl(al, (r & 3) + 8 * (r >> 2) + 4 * hi);
#pragma unroll
            for (int dt = 0; dt < 4; dt++) oacc[dt][r] *= ar;
          }
        }
        float rs = 0.f;
#pragma unroll
        for (int t = 0; t < 2; t++)
#pragma unroll
          for (int r = 0; r < 16; r++) {
            float pv = exp2f(sacc[t][r] - mrun);
            sacc[t][r] = pv;
            rs += pv;
          }
        rs += __shfl_xor(rs, 32);
        lrun += rs;
      }

      if (nt < last) WAITV(4); else WAITV(0);   // drain exactly V(nt)
      SCHED0(); SBAR(); CFENCE(); SCHED0();

      if (!skip) {
        u32x4 pa[4];
#pragma unroll
        for (int t = 0; t < 2; t++)
#pragma unroll
          for (int ksl = 0; ksl < 2; ksl++) {
            unsigned wa, wb, wc2, wd;
            asm("v_cvt_pk_bf16_f32 %0, %1, %2" : "=v"(wa)
                : "v"(sacc[t][8 * ksl + 0]), "v"(sacc[t][8 * ksl + 1]));
            asm("v_cvt_pk_bf16_f32 %0, %1, %2" : "=v"(wb)
                : "v"(sacc[t][8 * ksl + 2]), "v"(sacc[t][8 * ksl + 3]));
            asm("v_cvt_pk_bf16_f32 %0, %1, %2" : "=v"(wc2)
                : "v"(sacc[t][8 * ksl + 4]), "v"(sacc[t][8 * ksl + 5]));
            asm("v_cvt_pk_bf16_f32 %0, %1, %2" : "=v"(wd)
                : "v"(sacc[t][8 * ksl + 6]), "v"(sacc[t][8 * ksl + 7]));
            asm("v_permlane32_swap_b32 %0, %1" : "+v"(wa), "+v"(wc2));
            asm("v_permlane32_swap_b32 %0, %1" : "+v"(wb), "+v"(wd));
            u32x4 t4 = {wa, wb, wc2, wd};
            pa[t * 2 + ksl] = t4;
          }

#pragma unroll
        for (int ks = 0; ks < 4; ks++) {
          bf16x8 paf = __builtin_bit_cast(bf16x8, pa[ks]);
          bf16x8 bv[4];
#pragma unroll
          for (int dt = 0; dt < 4; dt++) {
            int rowv = dt * 32 + lq;
            bv[dt] = *reinterpret_cast<const bf16x8*>(
                Vb + rowv * 64 + ((((ks << 1) + hi) ^ (rowv & 7)) << 3));
          }
          __builtin_amdgcn_s_setprio(1);
#pragma unroll
          for (int dt = 0; dt < 4; dt++)
            oacc[dt] = __builtin_amdgcn_mfma_f32_32x32x16_bf16(paf, bv[dt], oacc[dt], 0, 0, 0);
          __builtin_amdgcn_s_setprio(0);
        }
      }

      if (nt < last) {
        SBAR(); SCHED0();          // all waves done reading Vb
        stageV(nt * 64 + 64);      // V(nt+1): +4 -> invariant restored
      }
      cur ^= 1;
    }

    float linv = 1.0f / lrun;
#pragma unroll
    for (int r = 0; r < 16; r++) {
      const int idx_r = (r & 3) + 8 * (r >> 2) + 4 * hi;
      float lr = __shfl(linv, idx_r);
      size_t base = ((size_t)b * S_ + (q0 + 32 * w + idx_r)) * NQ_ + h * D_ + lq;
#pragma unroll
      for (int dt = 0; dt < 4; dt++)
        out[base + dt * 32] = f2b(oacc[dt][r] * lr);
    }
  }
}

extern "C" void kernel_launch(void* const* d_in, const int* in_sizes, int n_in,
                              void* d_out, int out_size, void* d_ws, size_t ws_size,
                              hipStream_t stream) {
  const float* hidden = (const float*)d_in[0];
  const float* cosp   = (const float*)d_in[1];
  const float* sinp   = (const float*)d_in[2];
  const float* q_w    = (const float*)d_in[3];
  const float* k_w    = (const float*)d_in[4];
  const float* v_w    = (const float*)d_in[5];
  const float* o_w    = (const float*)d_in[6];
  const float* qnw    = (const float*)d_in[7];
  const float* knw    = (const float*)d_in[8];

  char* p = (char*)d_ws;
  u16* hb  = (u16*)p; p += (size_t)M_ * HID_ * 2;
  u16* qwt = (u16*)p; p += (size_t)NQ_ * HID_ * 2;
  u16* kwt = (u16*)p; p += (size_t)NKV_ * HID_ * 2;
  u16* vwt = (u16*)p; p += (size_t)NKV_ * HID_ * 2;
  u16* owt = (u16*)p; p += (size_t)HID_ * NQ_ * 2;
  u16* qb  = (u16*)p; p += (size_t)B_ * H_ * S_ * D_ * 2;
  u16* kb  = (u16*)p; p += (size_t)B_ * KVH_ * S_ * D_ * 2;
  u16* vb  = (u16*)p; p += (size_t)B_ * KVH_ * S_ * D_ * 2;  // V^T [B][KVH][D][S]
  u16* ab  = (u16*)p; p += (size_t)M_ * NQ_ * 2;

  k_prep<<<6656, 256, 0, stream>>>(hidden, hb, q_w, qwt, k_w, kwt, v_w, vwt, o_w, owt);
  k_gemm_q8<<<256, 512, 0, stream>>>(hb, qwt, qb);
  k_gemm_kv<<<256, 256, 0, stream>>>(hb, kwt, vwt, kb, vb);
  k_norm_rope<<<(B_ * H_ * S_ + B_ * KVH_ * S_) / 4, 256, 0, stream>>>(qb, kb, cosp, sinp, qnw, knw);
  k_attn<<<512, 256, 0, stream>>>(qb, kb, vb, ab);
  k_gemm_o<<<512, 256, 0, stream>>>(ab, owt, (float*)d_out);
}